// Round 3
// baseline (462.349 us; speedup 1.0000x reference)
//
#include <hip/hip_runtime.h>

#define THREADS 256

// ---------------- preprocessing: degree, dinv, CSR build ----------------

__global__ void k_count(const int* __restrict__ ei, int* __restrict__ cnt, int E) {
    int e = blockIdx.x * blockDim.x + threadIdx.x;
    if (e < E) atomicAdd(&cnt[ei[E + e]], 1);   // dst = ei[1][e]
}

__global__ void k_dinv(const int* __restrict__ cnt, float* __restrict__ dinv, int N) {
    int n = blockIdx.x * blockDim.x + threadIdx.x;
    if (n < N) dinv[n] = rsqrtf((float)cnt[n] + 1.0f);  // +1 self loop
}

// block-level exclusive scan (Hillis-Steele in LDS) + block sums
__global__ void k_scan1(const int* __restrict__ cnt, int* __restrict__ rp,
                        int* __restrict__ bsum, int N) {
    __shared__ int s[THREADS];
    int tid = threadIdx.x;
    int i = blockIdx.x * THREADS + tid;
    int v = (i < N) ? cnt[i] : 0;
    s[tid] = v;
    __syncthreads();
    for (int d = 1; d < THREADS; d <<= 1) {
        int t = (tid >= d) ? s[tid - d] : 0;
        __syncthreads();
        s[tid] += t;
        __syncthreads();
    }
    if (i < N) rp[i] = s[tid] - v;              // exclusive
    if (tid == THREADS - 1) bsum[blockIdx.x] = s[tid];
}

// scan of block sums; requires nb <= THREADS (N=50000 -> nb=196, ok)
__global__ void k_scan2(int* __restrict__ bsum, int nb) {
    __shared__ int s[THREADS];
    int tid = threadIdx.x;
    int v = (tid < nb) ? bsum[tid] : 0;
    s[tid] = v;
    __syncthreads();
    for (int d = 1; d < THREADS; d <<= 1) {
        int t = (tid >= d) ? s[tid - d] : 0;
        __syncthreads();
        s[tid] += t;
        __syncthreads();
    }
    if (tid < nb) bsum[tid] = s[tid] - v;       // exclusive
}

__global__ void k_add(int* __restrict__ rp, const int* __restrict__ bsum, int N, int E) {
    int i = blockIdx.x * THREADS + threadIdx.x;
    if (i < N) rp[i] += bsum[blockIdx.x];
    if (i == 0) rp[N] = E;
}

// edge packet: .x = src index, .y = bitcast(norm weight)
__global__ void k_scatter(const int* __restrict__ ei, const int* __restrict__ rp,
                          int* __restrict__ fill, const float* __restrict__ dinv,
                          int2* __restrict__ epack, int E) {
    int e = blockIdx.x * blockDim.x + threadIdx.x;
    if (e >= E) return;
    int s = ei[e], d = ei[E + e];
    int pos = rp[d] + atomicAdd(&fill[d], 1);
    int2 p;
    p.x = s;
    p.y = __float_as_int(dinv[s] * dinv[d]);
    epack[pos] = p;
}

// ---------------- group sizes via sorted-batch boundary detection (no atomics) ----

__global__ void k_ginit(int* __restrict__ gstart, int N, int G) {
    int g = threadIdx.x;
    if (g < G) gstart[g] = N;
}

__global__ void k_gbound(const int* __restrict__ batch, int* __restrict__ gstart, int N) {
    int n = blockIdx.x * blockDim.x + threadIdx.x;
    if (n >= N) return;
    if (n == 0) gstart[batch[0]] = 0;
    else if (batch[n] != batch[n - 1]) gstart[batch[n]] = n;
}

// single block of 128 threads: suffix-min fix (empty groups), then counts
__global__ void k_gfix(const int* __restrict__ gstart, float* __restrict__ gcnt, int N, int G) {
    __shared__ int s[129];
    int g = threadIdx.x;                         // 0..127
    s[g] = gstart[g];
    if (g == 0) s[128] = N;
    __syncthreads();
    for (int d = 1; d < 128; d <<= 1) {
        int v = s[g];
        int w = (g + d <= 128) ? s[g + d] : N;
        __syncthreads();
        s[g] = min(v, w);
        __syncthreads();
    }
    int nxt = (g < 127) ? s[g + 1] : N;
    gcnt[g] = (float)(nxt - s[g]);
}

// ---------------- fp32 GEMM: Y[N,128] = X[N,128] @ W[128,128] ----------------

#define BM 64
#define BK 32

__global__ __launch_bounds__(256) void k_gemm(const float* __restrict__ X,
                                              const float* __restrict__ W,
                                              float* __restrict__ Y, int N) {
    __shared__ float Xs[BK][BM + 1];   // transposed: Xs[k][m]
    __shared__ float Ws[BK][128];
    int tid = threadIdx.x;
    int tr = tid & 15, tc = tid >> 4;
    int r0 = tr * 4, c0 = tc * 8;
    int m0 = blockIdx.x * BM;

    float acc[4][8];
#pragma unroll
    for (int r = 0; r < 4; ++r)
#pragma unroll
        for (int c = 0; c < 8; ++c) acc[r][c] = 0.f;

    for (int k0 = 0; k0 < 128; k0 += BK) {
        __syncthreads();
#pragma unroll
        for (int i = 0; i < 2; ++i) {
            int idx = tid + 256 * i;             // 0..511
            int row = idx >> 3;                  // 0..63
            int kq  = idx & 7;
            float4 v = make_float4(0.f, 0.f, 0.f, 0.f);
            int grow = m0 + row;
            if (grow < N) v = *(const float4*)&X[(size_t)grow * 128 + k0 + kq * 4];
            Xs[kq * 4 + 0][row] = v.x;
            Xs[kq * 4 + 1][row] = v.y;
            Xs[kq * 4 + 2][row] = v.z;
            Xs[kq * 4 + 3][row] = v.w;
        }
#pragma unroll
        for (int i = 0; i < 4; ++i) {
            int idx = tid + 256 * i;             // 0..1023
            int krow = idx >> 5;
            int cq   = idx & 31;
            *(float4*)&Ws[krow][cq * 4] = *(const float4*)&W[(size_t)(k0 + krow) * 128 + cq * 4];
        }
        __syncthreads();

#pragma unroll
        for (int kk = 0; kk < BK; ++kk) {
            float4 a  = *(const float4*)&Xs[kk][r0];
            float4 b0 = *(const float4*)&Ws[kk][c0];
            float4 b1 = *(const float4*)&Ws[kk][c0 + 4];
            float av[4] = {a.x, a.y, a.z, a.w};
            float bv[8] = {b0.x, b0.y, b0.z, b0.w, b1.x, b1.y, b1.z, b1.w};
#pragma unroll
            for (int r = 0; r < 4; ++r)
#pragma unroll
                for (int c = 0; c < 8; ++c)
                    acc[r][c] = fmaf(av[r], bv[c], acc[r][c]);
        }
    }

#pragma unroll
    for (int r = 0; r < 4; ++r) {
        int row = m0 + r0 + r;
        if (row < N) {
            float4 o0 = make_float4(acc[r][0], acc[r][1], acc[r][2], acc[r][3]);
            float4 o1 = make_float4(acc[r][4], acc[r][5], acc[r][6], acc[r][7]);
            *(float4*)&Y[(size_t)row * 128 + c0]     = o0;
            *(float4*)&Y[(size_t)row * 128 + c0 + 4] = o1;
        }
    }
}

// ---------------- aggregation ----------------
// 2 nodes per wave (32 lanes x float4 each); 4-deep predicated edge unroll.
// out[n] = sum_e w_e * H[src_e] + dinv[n]^2 * H[n] + b ; relu. POOL=1 fuses pool sum.

template <int POOL>
__global__ __launch_bounds__(256) void k_aggregate(const float* __restrict__ H,
                                                   float* __restrict__ OUT,
                                                   const int* __restrict__ rp,
                                                   const int2* __restrict__ epack,
                                                   const float* __restrict__ dinv,
                                                   const float* __restrict__ bias,
                                                   const int* __restrict__ batch,
                                                   float* __restrict__ pooled, int N) {
    int half = threadIdx.x >> 5;                 // 0..7
    int lane = threadIdx.x & 31;
    int n = blockIdx.x * 8 + half;
    if (n >= N) return;
    int c0 = lane * 4;

    float4 acc = make_float4(0.f, 0.f, 0.f, 0.f);
    int beg = rp[n], end = rp[n + 1];

    for (int e = beg; e < end; e += 4) {
        int s[4]; float w[4];
#pragma unroll
        for (int j = 0; j < 4; ++j) {
            bool v = (e + j < end);
            int2 p = v ? epack[e + j] : make_int2(n, 0);
            s[j] = p.x;
            w[j] = v ? __int_as_float(p.y) : 0.f;
        }
#pragma unroll
        for (int j = 0; j < 4; ++j) {
            float4 hv = *(const float4*)&H[(size_t)s[j] * 128 + c0];
            acc.x = fmaf(w[j], hv.x, acc.x);
            acc.y = fmaf(w[j], hv.y, acc.y);
            acc.z = fmaf(w[j], hv.z, acc.z);
            acc.w = fmaf(w[j], hv.w, acc.w);
        }
    }

    float di = dinv[n];
    float sw = di * di;
    float4 hv = *(const float4*)&H[(size_t)n * 128 + c0];
    float4 bv = *(const float4*)&bias[c0];
    acc.x = fmaxf(fmaf(sw, hv.x, acc.x) + bv.x, 0.f);
    acc.y = fmaxf(fmaf(sw, hv.y, acc.y) + bv.y, 0.f);
    acc.z = fmaxf(fmaf(sw, hv.z, acc.z) + bv.z, 0.f);
    acc.w = fmaxf(fmaf(sw, hv.w, acc.w) + bv.w, 0.f);

    if (POOL) {
        int g = batch[n];
        atomicAdd(&pooled[g * 128 + c0 + 0], acc.x);
        atomicAdd(&pooled[g * 128 + c0 + 1], acc.y);
        atomicAdd(&pooled[g * 128 + c0 + 2], acc.z);
        atomicAdd(&pooled[g * 128 + c0 + 3], acc.w);
    } else {
        *(float4*)&OUT[(size_t)n * 128 + c0] = acc;
    }
}

// ---------------- final: out[G,64] = (pooled/cnt) @ lin_W + lin_b ----------------

__global__ void k_final(const float* __restrict__ pooled, const float* __restrict__ gcnt,
                        const float* __restrict__ lw, const float* __restrict__ lb,
                        float* __restrict__ out, int G) {
    int i = blockIdx.x * blockDim.x + threadIdx.x;
    if (i >= G * 64) return;
    int g = i >> 6, o = i & 63;
    float inv = 1.0f / fmaxf(gcnt[g], 1.0f);
    float acc = 0.f;
#pragma unroll
    for (int k = 0; k < 128; ++k) acc = fmaf(pooled[g * 128 + k], lw[k * 64 + o], acc);
    out[i] = acc * inv + lb[o];
}

// ---------------- launch ----------------

extern "C" void kernel_launch(void* const* d_in, const int* in_sizes, int n_in,
                              void* d_out, int out_size, void* d_ws, size_t ws_size,
                              hipStream_t stream) {
    const float* x   = (const float*)d_in[0];
    const int* ei    = (const int*)d_in[1];
    const int* batch = (const int*)d_in[2];
    const float* W0  = (const float*)d_in[3];
    const float* b0  = (const float*)d_in[4];
    const float* W1  = (const float*)d_in[5];
    const float* b1  = (const float*)d_in[6];
    const float* W2  = (const float*)d_in[7];
    const float* b2  = (const float*)d_in[8];
    const float* lw  = (const float*)d_in[9];
    const float* lb  = (const float*)d_in[10];
    float* out = (float*)d_out;

    const int N = in_sizes[2];        // 50000
    const int E = in_sizes[1] / 2;    // 600000
    const int G = 128;

    char* ws = (char*)d_ws;
    size_t off = 0;
    auto alloc = [&](size_t bytes) -> void* {
        void* p = ws + off;
        off += (bytes + 255) & ~(size_t)255;
        return p;
    };
    float* hA     = (float*)alloc((size_t)N * 128 * 4);
    float* hB     = (float*)alloc((size_t)N * 128 * 4);
    float* dinv   = (float*)alloc((size_t)N * 4);
    int*   cnt    = (int*)  alloc((size_t)N * 4);
    int*   rp     = (int*)  alloc((size_t)(N + 1) * 4);
    int2*  epack  = (int2*) alloc((size_t)E * 8);
    int*   bsum   = (int*)  alloc(1024 * 4);
    float* pooled = (float*)alloc((size_t)G * 128 * 4);
    float* gcnt   = (float*)alloc((size_t)G * 4);
    int*   gstart = (int*)  alloc((size_t)(G + 1) * 4);
    (void)ws_size; (void)n_in; (void)out_size;

    int nbN = (N + THREADS - 1) / THREADS;  // 196 (must be <= 256 for k_scan2)
    int nbE = (E + THREADS - 1) / THREADS;

    hipMemsetAsync(cnt, 0, (size_t)N * 4, stream);
    hipMemsetAsync(pooled, 0, (size_t)G * 128 * 4, stream);

    k_count<<<nbE, THREADS, 0, stream>>>(ei, cnt, E);
    k_dinv<<<nbN, THREADS, 0, stream>>>(cnt, dinv, N);
    k_scan1<<<nbN, THREADS, 0, stream>>>(cnt, rp, bsum, N);
    k_scan2<<<1, THREADS, 0, stream>>>(bsum, nbN);
    k_add<<<nbN, THREADS, 0, stream>>>(rp, bsum, N, E);
    hipMemsetAsync(cnt, 0, (size_t)N * 4, stream);   // reuse as fill counters
    k_scatter<<<nbE, THREADS, 0, stream>>>(ei, rp, cnt, dinv, epack, E);

    k_ginit<<<1, 128, 0, stream>>>(gstart, N, G);
    k_gbound<<<nbN, THREADS, 0, stream>>>(batch, gstart, N);
    k_gfix<<<1, 128, 0, stream>>>(gstart, gcnt, N, G);

    int gemm_grid = (N + BM - 1) / BM;
    int agg_grid  = (N + 7) / 8;

    k_gemm<<<gemm_grid, 256, 0, stream>>>(x, W0, hB, N);
    k_aggregate<0><<<agg_grid, 256, 0, stream>>>(hB, hA, rp, epack, dinv, b0, batch, pooled, N);
    k_gemm<<<gemm_grid, 256, 0, stream>>>(hA, W1, hB, N);
    k_aggregate<0><<<agg_grid, 256, 0, stream>>>(hB, hA, rp, epack, dinv, b1, batch, pooled, N);
    k_gemm<<<gemm_grid, 256, 0, stream>>>(hA, W2, hB, N);
    k_aggregate<1><<<agg_grid, 256, 0, stream>>>(hB, hA, rp, epack, dinv, b2, batch, pooled, N);
    k_final<<<(G * 64 + THREADS - 1) / THREADS, THREADS, 0, stream>>>(pooled, gcnt, lw, lb, out, G);
}

// Round 4
// 405.398 us; speedup vs baseline: 1.1405x; 1.1405x over previous
//
#include <hip/hip_runtime.h>

#define THREADS 256

// ---------------- preprocessing: degree, dinv, CSR build ----------------

__global__ void k_count(const int* __restrict__ ei, int* __restrict__ cnt, int E) {
    int e = blockIdx.x * blockDim.x + threadIdx.x;
    if (e < E) atomicAdd(&cnt[ei[E + e]], 1);   // dst = ei[1][e]
}

__global__ void k_dinv(const int* __restrict__ cnt, float* __restrict__ dinv, int N) {
    int n = blockIdx.x * blockDim.x + threadIdx.x;
    if (n < N) dinv[n] = rsqrtf((float)cnt[n] + 1.0f);  // +1 self loop
}

// block-level exclusive scan (Hillis-Steele in LDS) + block sums
__global__ void k_scan1(const int* __restrict__ cnt, int* __restrict__ rp,
                        int* __restrict__ bsum, int N) {
    __shared__ int s[THREADS];
    int tid = threadIdx.x;
    int i = blockIdx.x * THREADS + tid;
    int v = (i < N) ? cnt[i] : 0;
    s[tid] = v;
    __syncthreads();
    for (int d = 1; d < THREADS; d <<= 1) {
        int t = (tid >= d) ? s[tid - d] : 0;
        __syncthreads();
        s[tid] += t;
        __syncthreads();
    }
    if (i < N) rp[i] = s[tid] - v;              // exclusive
    if (tid == THREADS - 1) bsum[blockIdx.x] = s[tid];
}

// scan of block sums; requires nb <= THREADS (N=50000 -> nb=196, ok)
__global__ void k_scan2(int* __restrict__ bsum, int nb) {
    __shared__ int s[THREADS];
    int tid = threadIdx.x;
    int v = (tid < nb) ? bsum[tid] : 0;
    s[tid] = v;
    __syncthreads();
    for (int d = 1; d < THREADS; d <<= 1) {
        int t = (tid >= d) ? s[tid - d] : 0;
        __syncthreads();
        s[tid] += t;
        __syncthreads();
    }
    if (tid < nb) bsum[tid] = s[tid] - v;       // exclusive
}

__global__ void k_add(int* __restrict__ rp, const int* __restrict__ bsum, int N, int E) {
    int i = blockIdx.x * THREADS + threadIdx.x;
    if (i < N) rp[i] += bsum[blockIdx.x];
    if (i == 0) rp[N] = E;
}

// edge packet: .x = src index, .y = bitcast(norm weight)
__global__ void k_scatter(const int* __restrict__ ei, const int* __restrict__ rp,
                          int* __restrict__ fill, const float* __restrict__ dinv,
                          int2* __restrict__ epack, int E) {
    int e = blockIdx.x * blockDim.x + threadIdx.x;
    if (e >= E) return;
    int s = ei[e], d = ei[E + e];
    int pos = rp[d] + atomicAdd(&fill[d], 1);
    int2 p;
    p.x = s;
    p.y = __float_as_int(dinv[s] * dinv[d]);
    epack[pos] = p;
}

// ---------------- group sizes via sorted-batch boundary detection (no atomics) ----

__global__ void k_ginit(int* __restrict__ gstart, int N, int G) {
    int g = threadIdx.x;
    if (g < G) gstart[g] = N;
}

__global__ void k_gbound(const int* __restrict__ batch, int* __restrict__ gstart, int N) {
    int n = blockIdx.x * blockDim.x + threadIdx.x;
    if (n >= N) return;
    if (n == 0) gstart[batch[0]] = 0;
    else if (batch[n] != batch[n - 1]) gstart[batch[n]] = n;
}

// single block of 128 threads: suffix-min fix (empty groups), then counts
__global__ void k_gfix(const int* __restrict__ gstart, float* __restrict__ gcnt, int N, int G) {
    __shared__ int s[129];
    int g = threadIdx.x;                         // 0..127
    s[g] = gstart[g];
    if (g == 0) s[128] = N;
    __syncthreads();
    for (int d = 1; d < 128; d <<= 1) {
        int v = s[g];
        int w = (g + d <= 128) ? s[g + d] : N;
        __syncthreads();
        s[g] = min(v, w);
        __syncthreads();
    }
    int nxt = (g < 127) ? s[g + 1] : N;
    gcnt[g] = (float)(nxt - s[g]);
}

// ---------------- fp32 GEMM: Y[N,128] = X[N,128] @ W[128,128] ----------------

#define BM 64
#define BK 32

__global__ __launch_bounds__(256) void k_gemm(const float* __restrict__ X,
                                              const float* __restrict__ W,
                                              float* __restrict__ Y, int N) {
    __shared__ float Xs[BK][BM + 1];   // transposed: Xs[k][m]
    __shared__ float Ws[BK][128];
    int tid = threadIdx.x;
    int tr = tid & 15, tc = tid >> 4;
    int r0 = tr * 4, c0 = tc * 8;
    int m0 = blockIdx.x * BM;

    float acc[4][8];
#pragma unroll
    for (int r = 0; r < 4; ++r)
#pragma unroll
        for (int c = 0; c < 8; ++c) acc[r][c] = 0.f;

    for (int k0 = 0; k0 < 128; k0 += BK) {
        __syncthreads();
#pragma unroll
        for (int i = 0; i < 2; ++i) {
            int idx = tid + 256 * i;             // 0..511
            int row = idx >> 3;                  // 0..63
            int kq  = idx & 7;
            float4 v = make_float4(0.f, 0.f, 0.f, 0.f);
            int grow = m0 + row;
            if (grow < N) v = *(const float4*)&X[(size_t)grow * 128 + k0 + kq * 4];
            Xs[kq * 4 + 0][row] = v.x;
            Xs[kq * 4 + 1][row] = v.y;
            Xs[kq * 4 + 2][row] = v.z;
            Xs[kq * 4 + 3][row] = v.w;
        }
#pragma unroll
        for (int i = 0; i < 4; ++i) {
            int idx = tid + 256 * i;             // 0..1023
            int krow = idx >> 5;
            int cq   = idx & 31;
            *(float4*)&Ws[krow][cq * 4] = *(const float4*)&W[(size_t)(k0 + krow) * 128 + cq * 4];
        }
        __syncthreads();

#pragma unroll
        for (int kk = 0; kk < BK; ++kk) {
            float4 a  = *(const float4*)&Xs[kk][r0];
            float4 b0 = *(const float4*)&Ws[kk][c0];
            float4 b1 = *(const float4*)&Ws[kk][c0 + 4];
            float av[4] = {a.x, a.y, a.z, a.w};
            float bv[8] = {b0.x, b0.y, b0.z, b0.w, b1.x, b1.y, b1.z, b1.w};
#pragma unroll
            for (int r = 0; r < 4; ++r)
#pragma unroll
                for (int c = 0; c < 8; ++c)
                    acc[r][c] = fmaf(av[r], bv[c], acc[r][c]);
        }
    }

#pragma unroll
    for (int r = 0; r < 4; ++r) {
        int row = m0 + r0 + r;
        if (row < N) {
            float4 o0 = make_float4(acc[r][0], acc[r][1], acc[r][2], acc[r][3]);
            float4 o1 = make_float4(acc[r][4], acc[r][5], acc[r][6], acc[r][7]);
            *(float4*)&Y[(size_t)row * 128 + c0]     = o0;
            *(float4*)&Y[(size_t)row * 128 + c0 + 4] = o1;
        }
    }
}

// ---------------- aggregation ----------------
// One node per 64-lane wave (float2/lane), 4-deep edge unroll with wave-uniform
// trip count: tail edges clamp the (uniform) index and zero the weight, so the
// edge-packet loads stay scalar and there is no intra-wave divergence.

template <int POOL>
__global__ __launch_bounds__(256) void k_aggregate(const float* __restrict__ H,
                                                   float* __restrict__ OUT,
                                                   const int* __restrict__ rp,
                                                   const int2* __restrict__ epack,
                                                   const float* __restrict__ dinv,
                                                   const float* __restrict__ bias,
                                                   const int* __restrict__ batch,
                                                   float* __restrict__ pooled, int N) {
    int wid  = threadIdx.x >> 6;
    int lane = threadIdx.x & 63;
    int n = blockIdx.x * 4 + wid;
    if (n >= N) return;
    int c0 = lane * 2;

    float2 acc = make_float2(0.f, 0.f);
    int beg = rp[n], end = rp[n + 1];

    for (int e = beg; e < end; e += 4) {
        int2 p[4];
#pragma unroll
        for (int j = 0; j < 4; ++j) {
            int idx = e + j;
            p[j] = epack[idx < end ? idx : end - 1];   // uniform address, clamped tail
        }
#pragma unroll
        for (int j = 0; j < 4; ++j) {
            float w = (e + j < end) ? __int_as_float(p[j].y) : 0.f;
            float2 hv = *(const float2*)&H[(size_t)p[j].x * 128 + c0];
            acc.x = fmaf(w, hv.x, acc.x);
            acc.y = fmaf(w, hv.y, acc.y);
        }
    }

    float di = dinv[n];
    float sw = di * di;
    float2 hv = *(const float2*)&H[(size_t)n * 128 + c0];
    acc.x = fmaf(sw, hv.x, acc.x);
    acc.y = fmaf(sw, hv.y, acc.y);
    acc.x = fmaxf(acc.x + bias[c0], 0.f);
    acc.y = fmaxf(acc.y + bias[c0 + 1], 0.f);

    if (POOL) {
        int g = batch[n];
        atomicAdd(&pooled[g * 128 + c0], acc.x);
        atomicAdd(&pooled[g * 128 + c0 + 1], acc.y);
    } else {
        float2 o; o.x = acc.x; o.y = acc.y;
        *(float2*)&OUT[(size_t)n * 128 + c0] = o;
    }
}

// ---------------- final: out[G,64] = (pooled/cnt) @ lin_W + lin_b ----------------

__global__ void k_final(const float* __restrict__ pooled, const float* __restrict__ gcnt,
                        const float* __restrict__ lw, const float* __restrict__ lb,
                        float* __restrict__ out, int G) {
    int i = blockIdx.x * blockDim.x + threadIdx.x;
    if (i >= G * 64) return;
    int g = i >> 6, o = i & 63;
    float inv = 1.0f / fmaxf(gcnt[g], 1.0f);
    float acc = 0.f;
#pragma unroll
    for (int k = 0; k < 128; ++k) acc = fmaf(pooled[g * 128 + k], lw[k * 64 + o], acc);
    out[i] = acc * inv + lb[o];
}

// ---------------- launch ----------------

extern "C" void kernel_launch(void* const* d_in, const int* in_sizes, int n_in,
                              void* d_out, int out_size, void* d_ws, size_t ws_size,
                              hipStream_t stream) {
    const float* x   = (const float*)d_in[0];
    const int* ei    = (const int*)d_in[1];
    const int* batch = (const int*)d_in[2];
    const float* W0  = (const float*)d_in[3];
    const float* b0  = (const float*)d_in[4];
    const float* W1  = (const float*)d_in[5];
    const float* b1  = (const float*)d_in[6];
    const float* W2  = (const float*)d_in[7];
    const float* b2  = (const float*)d_in[8];
    const float* lw  = (const float*)d_in[9];
    const float* lb  = (const float*)d_in[10];
    float* out = (float*)d_out;

    const int N = in_sizes[2];        // 50000
    const int E = in_sizes[1] / 2;    // 600000
    const int G = 128;

    char* ws = (char*)d_ws;
    size_t off = 0;
    auto alloc = [&](size_t bytes) -> void* {
        void* p = ws + off;
        off += (bytes + 255) & ~(size_t)255;
        return p;
    };
    float* hA     = (float*)alloc((size_t)N * 128 * 4);
    float* hB     = (float*)alloc((size_t)N * 128 * 4);
    float* dinv   = (float*)alloc((size_t)N * 4);
    int*   cnt    = (int*)  alloc((size_t)N * 4);
    int*   rp     = (int*)  alloc((size_t)(N + 1) * 4);
    int2*  epack  = (int2*) alloc((size_t)E * 8);
    int*   bsum   = (int*)  alloc(1024 * 4);
    float* pooled = (float*)alloc((size_t)G * 128 * 4);
    float* gcnt   = (float*)alloc((size_t)G * 4);
    int*   gstart = (int*)  alloc((size_t)(G + 1) * 4);
    (void)ws_size; (void)n_in; (void)out_size;

    int nbN = (N + THREADS - 1) / THREADS;  // 196 (must be <= 256 for k_scan2)
    int nbE = (E + THREADS - 1) / THREADS;

    hipMemsetAsync(cnt, 0, (size_t)N * 4, stream);
    hipMemsetAsync(pooled, 0, (size_t)G * 128 * 4, stream);

    k_count<<<nbE, THREADS, 0, stream>>>(ei, cnt, E);
    k_dinv<<<nbN, THREADS, 0, stream>>>(cnt, dinv, N);
    k_scan1<<<nbN, THREADS, 0, stream>>>(cnt, rp, bsum, N);
    k_scan2<<<1, THREADS, 0, stream>>>(bsum, nbN);
    k_add<<<nbN, THREADS, 0, stream>>>(rp, bsum, N, E);
    hipMemsetAsync(cnt, 0, (size_t)N * 4, stream);   // reuse as fill counters
    k_scatter<<<nbE, THREADS, 0, stream>>>(ei, rp, cnt, dinv, epack, E);

    k_ginit<<<1, 128, 0, stream>>>(gstart, N, G);
    k_gbound<<<nbN, THREADS, 0, stream>>>(batch, gstart, N);
    k_gfix<<<1, 128, 0, stream>>>(gstart, gcnt, N, G);

    int gemm_grid = (N + BM - 1) / BM;
    int agg_grid  = (N + 3) / 4;

    k_gemm<<<gemm_grid, 256, 0, stream>>>(x, W0, hB, N);
    k_aggregate<0><<<agg_grid, 256, 0, stream>>>(hB, hA, rp, epack, dinv, b0, batch, pooled, N);
    k_gemm<<<gemm_grid, 256, 0, stream>>>(hA, W1, hB, N);
    k_aggregate<0><<<agg_grid, 256, 0, stream>>>(hB, hA, rp, epack, dinv, b1, batch, pooled, N);
    k_gemm<<<gemm_grid, 256, 0, stream>>>(hA, W2, hB, N);
    k_aggregate<1><<<agg_grid, 256, 0, stream>>>(hB, hA, rp, epack, dinv, b2, batch, pooled, N);
    k_final<<<(G * 64 + THREADS - 1) / THREADS, THREADS, 0, stream>>>(pooled, gcnt, lw, lb, out, G);
}

// Round 5
// 366.220 us; speedup vs baseline: 1.2625x; 1.1070x over previous
//
#include <hip/hip_runtime.h>
#include <hip/hip_fp16.h>

#define THREADS 256

// ---------------- preprocessing: degree, dinv, CSR build ----------------

__global__ void k_count(const int* __restrict__ ei, int* __restrict__ cnt, int E) {
    int e = blockIdx.x * blockDim.x + threadIdx.x;
    if (e < E) atomicAdd(&cnt[ei[E + e]], 1);   // dst = ei[1][e]
}

__global__ void k_dinv(const int* __restrict__ cnt, float* __restrict__ dinv, int N) {
    int n = blockIdx.x * blockDim.x + threadIdx.x;
    if (n < N) dinv[n] = rsqrtf((float)cnt[n] + 1.0f);  // +1 self loop
}

// block-level exclusive scan (Hillis-Steele in LDS) + block sums
__global__ void k_scan1(const int* __restrict__ cnt, int* __restrict__ rp,
                        int* __restrict__ bsum, int N) {
    __shared__ int s[THREADS];
    int tid = threadIdx.x;
    int i = blockIdx.x * THREADS + tid;
    int v = (i < N) ? cnt[i] : 0;
    s[tid] = v;
    __syncthreads();
    for (int d = 1; d < THREADS; d <<= 1) {
        int t = (tid >= d) ? s[tid - d] : 0;
        __syncthreads();
        s[tid] += t;
        __syncthreads();
    }
    if (i < N) rp[i] = s[tid] - v;              // exclusive
    if (tid == THREADS - 1) bsum[blockIdx.x] = s[tid];
}

// scan of block sums; requires nb <= THREADS (N=50000 -> nb=196, ok)
__global__ void k_scan2(int* __restrict__ bsum, int nb) {
    __shared__ int s[THREADS];
    int tid = threadIdx.x;
    int v = (tid < nb) ? bsum[tid] : 0;
    s[tid] = v;
    __syncthreads();
    for (int d = 1; d < THREADS; d <<= 1) {
        int t = (tid >= d) ? s[tid - d] : 0;
        __syncthreads();
        s[tid] += t;
        __syncthreads();
    }
    if (tid < nb) bsum[tid] = s[tid] - v;       // exclusive
}

__global__ void k_add(int* __restrict__ rp, const int* __restrict__ bsum, int N, int E) {
    int i = blockIdx.x * THREADS + threadIdx.x;
    if (i < N) rp[i] += bsum[blockIdx.x];
    if (i == 0) rp[N] = E;
}

// edge packet: .x = src index, .y = bitcast(norm weight)
__global__ void k_scatter(const int* __restrict__ ei, const int* __restrict__ rp,
                          int* __restrict__ fill, const float* __restrict__ dinv,
                          int2* __restrict__ epack, int E) {
    int e = blockIdx.x * blockDim.x + threadIdx.x;
    if (e >= E) return;
    int s = ei[e], d = ei[E + e];
    int pos = rp[d] + atomicAdd(&fill[d], 1);
    int2 p;
    p.x = s;
    p.y = __float_as_int(dinv[s] * dinv[d]);
    epack[pos] = p;
}

// ---------------- group sizes via sorted-batch boundary detection (no atomics) ----

__global__ void k_ginit(int* __restrict__ gstart, int N, int G) {
    int g = threadIdx.x;
    if (g < G) gstart[g] = N;
}

__global__ void k_gbound(const int* __restrict__ batch, int* __restrict__ gstart, int N) {
    int n = blockIdx.x * blockDim.x + threadIdx.x;
    if (n >= N) return;
    if (n == 0) gstart[batch[0]] = 0;
    else if (batch[n] != batch[n - 1]) gstart[batch[n]] = n;
}

// single block of 128 threads: suffix-min fix (empty groups), then counts
__global__ void k_gfix(const int* __restrict__ gstart, float* __restrict__ gcnt, int N, int G) {
    __shared__ int s[129];
    int g = threadIdx.x;                         // 0..127
    s[g] = gstart[g];
    if (g == 0) s[128] = N;
    __syncthreads();
    for (int d = 1; d < 128; d <<= 1) {
        int v = s[g];
        int w = (g + d <= 128) ? s[g + d] : N;
        __syncthreads();
        s[g] = min(v, w);
        __syncthreads();
    }
    int nxt = (g < 127) ? s[g + 1] : N;
    gcnt[g] = (float)(nxt - s[g]);
}

// ---------------- fp32 GEMM: Y[N,128] = X[N,128] @ W[128,128] ----------------
// Also emits an fp16 mirror Yh for the aggregation gather.

#define BM 64
#define BK 32

__global__ __launch_bounds__(256) void k_gemm(const float* __restrict__ X,
                                              const float* __restrict__ W,
                                              float* __restrict__ Y,
                                              __half* __restrict__ Yh, int N) {
    __shared__ float Xs[BK][BM + 1];   // transposed: Xs[k][m]
    __shared__ float Ws[BK][128];
    int tid = threadIdx.x;
    int tr = tid & 15, tc = tid >> 4;
    int r0 = tr * 4, c0 = tc * 8;
    int m0 = blockIdx.x * BM;

    float acc[4][8];
#pragma unroll
    for (int r = 0; r < 4; ++r)
#pragma unroll
        for (int c = 0; c < 8; ++c) acc[r][c] = 0.f;

    for (int k0 = 0; k0 < 128; k0 += BK) {
        __syncthreads();
#pragma unroll
        for (int i = 0; i < 2; ++i) {
            int idx = tid + 256 * i;             // 0..511
            int row = idx >> 3;                  // 0..63
            int kq  = idx & 7;
            float4 v = make_float4(0.f, 0.f, 0.f, 0.f);
            int grow = m0 + row;
            if (grow < N) v = *(const float4*)&X[(size_t)grow * 128 + k0 + kq * 4];
            Xs[kq * 4 + 0][row] = v.x;
            Xs[kq * 4 + 1][row] = v.y;
            Xs[kq * 4 + 2][row] = v.z;
            Xs[kq * 4 + 3][row] = v.w;
        }
#pragma unroll
        for (int i = 0; i < 4; ++i) {
            int idx = tid + 256 * i;             // 0..1023
            int krow = idx >> 5;
            int cq   = idx & 31;
            *(float4*)&Ws[krow][cq * 4] = *(const float4*)&W[(size_t)(k0 + krow) * 128 + cq * 4];
        }
        __syncthreads();

#pragma unroll
        for (int kk = 0; kk < BK; ++kk) {
            float4 a  = *(const float4*)&Xs[kk][r0];
            float4 b0 = *(const float4*)&Ws[kk][c0];
            float4 b1 = *(const float4*)&Ws[kk][c0 + 4];
            float av[4] = {a.x, a.y, a.z, a.w};
            float bv[8] = {b0.x, b0.y, b0.z, b0.w, b1.x, b1.y, b1.z, b1.w};
#pragma unroll
            for (int r = 0; r < 4; ++r)
#pragma unroll
                for (int c = 0; c < 8; ++c)
                    acc[r][c] = fmaf(av[r], bv[c], acc[r][c]);
        }
    }

#pragma unroll
    for (int r = 0; r < 4; ++r) {
        int row = m0 + r0 + r;
        if (row < N) {
            float4 o0 = make_float4(acc[r][0], acc[r][1], acc[r][2], acc[r][3]);
            float4 o1 = make_float4(acc[r][4], acc[r][5], acc[r][6], acc[r][7]);
            *(float4*)&Y[(size_t)row * 128 + c0]     = o0;
            *(float4*)&Y[(size_t)row * 128 + c0 + 4] = o1;
            __half hbuf[8];
#pragma unroll
            for (int c = 0; c < 8; ++c) hbuf[c] = __float2half(acc[r][c]);
            *(int4*)&Yh[(size_t)row * 128 + c0] = *(int4*)hbuf;   // 8 halves = 16B
        }
    }
}

// ---------------- aggregation ----------------
// One node per 64-lane wave; edge gathers read the fp16 mirror (__half2/lane,
// 256B per row), accumulate fp32. Self-loop term + bias from fp32. 4-deep
// edge unroll with wave-uniform trip count (clamped index, zeroed weight).

template <int POOL>
__global__ __launch_bounds__(256) void k_aggregate(const float* __restrict__ H,
                                                   const __half* __restrict__ Hh,
                                                   float* __restrict__ OUT,
                                                   const int* __restrict__ rp,
                                                   const int2* __restrict__ epack,
                                                   const float* __restrict__ dinv,
                                                   const float* __restrict__ bias,
                                                   const int* __restrict__ batch,
                                                   float* __restrict__ pooled, int N) {
    int wid  = threadIdx.x >> 6;
    int lane = threadIdx.x & 63;
    int n = blockIdx.x * 4 + wid;
    if (n >= N) return;
    int c0 = lane * 2;

    float2 acc = make_float2(0.f, 0.f);
    int beg = rp[n], end = rp[n + 1];

    for (int e = beg; e < end; e += 4) {
        int2 p[4];
#pragma unroll
        for (int j = 0; j < 4; ++j) {
            int idx = e + j;
            p[j] = epack[idx < end ? idx : end - 1];   // uniform address, clamped tail
        }
#pragma unroll
        for (int j = 0; j < 4; ++j) {
            float w = (e + j < end) ? __int_as_float(p[j].y) : 0.f;
            __half2 hh = *(const __half2*)&Hh[(size_t)p[j].x * 128 + c0];
            acc.x = fmaf(w, __low2float(hh), acc.x);
            acc.y = fmaf(w, __high2float(hh), acc.y);
        }
    }

    float di = dinv[n];
    float sw = di * di;
    float2 hv = *(const float2*)&H[(size_t)n * 128 + c0];
    acc.x = fmaf(sw, hv.x, acc.x);
    acc.y = fmaf(sw, hv.y, acc.y);
    acc.x = fmaxf(acc.x + bias[c0], 0.f);
    acc.y = fmaxf(acc.y + bias[c0 + 1], 0.f);

    if (POOL) {
        int g = batch[n];
        atomicAdd(&pooled[g * 128 + c0], acc.x);
        atomicAdd(&pooled[g * 128 + c0 + 1], acc.y);
    } else {
        float2 o; o.x = acc.x; o.y = acc.y;
        *(float2*)&OUT[(size_t)n * 128 + c0] = o;
    }
}

// ---------------- final: out[G,64] = (pooled/cnt) @ lin_W + lin_b ----------------

__global__ void k_final(const float* __restrict__ pooled, const float* __restrict__ gcnt,
                        const float* __restrict__ lw, const float* __restrict__ lb,
                        float* __restrict__ out, int G) {
    int i = blockIdx.x * blockDim.x + threadIdx.x;
    if (i >= G * 64) return;
    int g = i >> 6, o = i & 63;
    float inv = 1.0f / fmaxf(gcnt[g], 1.0f);
    float acc = 0.f;
#pragma unroll
    for (int k = 0; k < 128; ++k) acc = fmaf(pooled[g * 128 + k], lw[k * 64 + o], acc);
    out[i] = acc * inv + lb[o];
}

// ---------------- launch ----------------

extern "C" void kernel_launch(void* const* d_in, const int* in_sizes, int n_in,
                              void* d_out, int out_size, void* d_ws, size_t ws_size,
                              hipStream_t stream) {
    const float* x   = (const float*)d_in[0];
    const int* ei    = (const int*)d_in[1];
    const int* batch = (const int*)d_in[2];
    const float* W0  = (const float*)d_in[3];
    const float* b0  = (const float*)d_in[4];
    const float* W1  = (const float*)d_in[5];
    const float* b1  = (const float*)d_in[6];
    const float* W2  = (const float*)d_in[7];
    const float* b2  = (const float*)d_in[8];
    const float* lw  = (const float*)d_in[9];
    const float* lb  = (const float*)d_in[10];
    float* out = (float*)d_out;

    const int N = in_sizes[2];        // 50000
    const int E = in_sizes[1] / 2;    // 600000
    const int G = 128;

    char* ws = (char*)d_ws;
    size_t off = 0;
    auto alloc = [&](size_t bytes) -> void* {
        void* p = ws + off;
        off += (bytes + 255) & ~(size_t)255;
        return p;
    };
    float*  hA     = (float*) alloc((size_t)N * 128 * 4);
    float*  hB     = (float*) alloc((size_t)N * 128 * 4);
    __half* hBh    = (__half*)alloc((size_t)N * 128 * 2);
    float*  dinv   = (float*) alloc((size_t)N * 4);
    int*    cnt    = (int*)   alloc((size_t)N * 4);
    int*    rp     = (int*)   alloc((size_t)(N + 1) * 4);
    int2*   epack  = (int2*)  alloc((size_t)E * 8);
    int*    bsum   = (int*)   alloc(1024 * 4);
    float*  pooled = (float*) alloc((size_t)G * 128 * 4);
    float*  gcnt   = (float*) alloc((size_t)G * 4);
    int*    gstart = (int*)   alloc((size_t)(G + 1) * 4);
    (void)ws_size; (void)n_in; (void)out_size;

    int nbN = (N + THREADS - 1) / THREADS;  // 196 (must be <= 256 for k_scan2)
    int nbE = (E + THREADS - 1) / THREADS;

    hipMemsetAsync(cnt, 0, (size_t)N * 4, stream);
    hipMemsetAsync(pooled, 0, (size_t)G * 128 * 4, stream);

    k_count<<<nbE, THREADS, 0, stream>>>(ei, cnt, E);
    k_dinv<<<nbN, THREADS, 0, stream>>>(cnt, dinv, N);
    k_scan1<<<nbN, THREADS, 0, stream>>>(cnt, rp, bsum, N);
    k_scan2<<<1, THREADS, 0, stream>>>(bsum, nbN);
    k_add<<<nbN, THREADS, 0, stream>>>(rp, bsum, N, E);
    hipMemsetAsync(cnt, 0, (size_t)N * 4, stream);   // reuse as fill counters
    k_scatter<<<nbE, THREADS, 0, stream>>>(ei, rp, cnt, dinv, epack, E);

    k_ginit<<<1, 128, 0, stream>>>(gstart, N, G);
    k_gbound<<<nbN, THREADS, 0, stream>>>(batch, gstart, N);
    k_gfix<<<1, 128, 0, stream>>>(gstart, gcnt, N, G);

    int gemm_grid = (N + BM - 1) / BM;
    int agg_grid  = (N + 3) / 4;

    k_gemm<<<gemm_grid, 256, 0, stream>>>(x, W0, hB, hBh, N);
    k_aggregate<0><<<agg_grid, 256, 0, stream>>>(hB, hBh, hA, rp, epack, dinv, b0, batch, pooled, N);
    k_gemm<<<gemm_grid, 256, 0, stream>>>(hA, W1, hB, hBh, N);
    k_aggregate<0><<<agg_grid, 256, 0, stream>>>(hB, hBh, hA, rp, epack, dinv, b1, batch, pooled, N);
    k_gemm<<<gemm_grid, 256, 0, stream>>>(hA, W2, hB, hBh, N);
    k_aggregate<1><<<agg_grid, 256, 0, stream>>>(hB, hBh, hA, rp, epack, dinv, b2, batch, pooled, N);
    k_final<<<(G * 64 + THREADS - 1) / THREADS, THREADS, 0, stream>>>(pooled, gcnt, lw, lb, out, G);
}